// Round 6
// baseline (45.969 us; speedup 1.0000x reference)
//
#include <hip/hip_runtime.h>
#include <hip/hip_bf16.h>

// SoftToHardQuantize forward == hard quantize (soft path cancels in value).
// Exact np.argmin(|x - C[l]|) semantics preserved via exact thresholds:
// prep sorts codes (parallel rank sort) and binary-searches, in ordered-
// float-bit space, the exact first float where the argmin pairwise predicate
// (strict <, tie -> lower original index) flips for each adjacent sorted pair.
// Verified exact in R5 (absmax 0.0).
//
// R5 lesson (rule #20): insertion sort with runtime-indexed register arrays
// went to scratch -> ~15us prep. R6: rank sort, zero arrays, zero scratch.
// R6 main: sorted[count] == cndmask chain q = (x>=T_k) ? SV[k+1] : q
// (monotone thresholds) -> 30 VALU/elem, no LDS, values/thresholds in SGPRs.

#define NCODES 16

typedef float vfloat4 __attribute__((ext_vector_type(4)));

__device__ __forceinline__ unsigned f2o(float f) {
    unsigned u = __float_as_uint(f);
    return (u & 0x80000000u) ? ~u : (u | 0x80000000u);
}
__device__ __forceinline__ float o2f(unsigned o) {
    unsigned u = (o & 0x80000000u) ? (o & 0x7fffffffu) : ~o;
    return __uint_as_float(u);
}

// ws layout: [0..15] sorted codes, [16..30] thresholds
__global__ void stq_prep(const float* __restrict__ C, float* __restrict__ ws, int L) {
    __shared__ float s_val[NCODES];
    __shared__ int   s_idx[NCODES];
    const int t = threadIdx.x;

    // parallel stable rank sort (no register arrays -> no scratch)
    if (t < L) {
        float x = C[t];
        int rank = 0;
        for (int j = 0; j < L; ++j) {
            float cj = C[j];
            rank += (cj < x || (cj == x && j < t)) ? 1 : 0;
        }
        s_val[rank] = x;
        s_idx[rank] = t;
    }
    __syncthreads();

    if (t < L) ws[t] = s_val[t];

    if (t < L - 1) {
        float a = s_val[t], b = s_val[t + 1];
        int   ia = s_idx[t], ib = s_idx[t + 1];
        float T;
        if (a == b) {
            // duplicate codes: stable sort => ia<ib => lower index always wins
            T = 3.4e38f;
        } else {
            // p(x): upper code wins per np.argmin. p(a)=false, p(b)=true,
            // monotone on [a,b] -> binary search in ordered-bit space.
            unsigned lo = f2o(a), hi = f2o(b);
            while (hi - lo > 1u) {
                unsigned mid = lo + (hi - lo) / 2u;
                float x  = o2f(mid);
                float da = fabsf(x - a);
                float db = fabsf(x - b);
                bool p = (db < da) || (db == da && ib < ia);
                if (p) hi = mid; else lo = mid;
            }
            T = o2f(hi);  // smallest float where upper wins: x >= T
        }
        ws[NCODES + t] = T;
    }
}

__device__ __forceinline__ float quant1(float x, const float* T, const float* SV) {
    float q = SV[0];
#pragma unroll
    for (int k = 0; k < NCODES - 1; ++k) {
        q = (x >= T[k]) ? SV[k + 1] : q;   // v_cmp + v_cndmask, SGPR operands
    }
    return q;
}

__global__ __launch_bounds__(256) void stq_main(const vfloat4* __restrict__ in,
                                                vfloat4* __restrict__ out,
                                                const float* __restrict__ ws,
                                                int n4,
                                                const float* __restrict__ in_tail,
                                                float* __restrict__ out_tail,
                                                int n_tail) {
    // uniform -> SGPRs
    float SV[NCODES], T[NCODES - 1];
#pragma unroll
    for (int k = 0; k < NCODES; ++k) SV[k] = ws[k];
#pragma unroll
    for (int k = 0; k < NCODES - 1; ++k) T[k] = ws[NCODES + k];

    const int stride = gridDim.x * blockDim.x;
    int i = blockIdx.x * blockDim.x + threadIdx.x;

    // 4-deep: all 4 dwordx4 loads in flight before compute
    for (; i + 3 * stride < n4; i += 4 * stride) {
        vfloat4 v0 = in[i];
        vfloat4 v1 = in[i + stride];
        vfloat4 v2 = in[i + 2 * stride];
        vfloat4 v3 = in[i + 3 * stride];

        vfloat4 r0, r1, r2, r3;
        r0.x = quant1(v0.x, T, SV); r0.y = quant1(v0.y, T, SV);
        r0.z = quant1(v0.z, T, SV); r0.w = quant1(v0.w, T, SV);
        r1.x = quant1(v1.x, T, SV); r1.y = quant1(v1.y, T, SV);
        r1.z = quant1(v1.z, T, SV); r1.w = quant1(v1.w, T, SV);
        r2.x = quant1(v2.x, T, SV); r2.y = quant1(v2.y, T, SV);
        r2.z = quant1(v2.z, T, SV); r2.w = quant1(v2.w, T, SV);
        r3.x = quant1(v3.x, T, SV); r3.y = quant1(v3.y, T, SV);
        r3.z = quant1(v3.z, T, SV); r3.w = quant1(v3.w, T, SV);

        __builtin_nontemporal_store(r0, &out[i]);
        __builtin_nontemporal_store(r1, &out[i + stride]);
        __builtin_nontemporal_store(r2, &out[i + 2 * stride]);
        __builtin_nontemporal_store(r3, &out[i + 3 * stride]);
    }
    for (; i < n4; i += stride) {
        vfloat4 v = in[i];
        vfloat4 r;
        r.x = quant1(v.x, T, SV); r.y = quant1(v.y, T, SV);
        r.z = quant1(v.z, T, SV); r.w = quant1(v.w, T, SV);
        __builtin_nontemporal_store(r, &out[i]);
    }

    int t = blockIdx.x * blockDim.x + threadIdx.x;
    if (t < n_tail) {
        out_tail[t] = quant1(in_tail[t], T, SV);
    }
}

extern "C" void kernel_launch(void* const* d_in, const int* in_sizes, int n_in,
                              void* d_out, int out_size, void* d_ws, size_t ws_size,
                              hipStream_t stream) {
    const float* inp = (const float*)d_in[0];
    const float* C   = (const float*)d_in[1];
    // d_in[2] = sigma: unused (forward value is exactly the hard quantize)
    float* out = (float*)d_out;
    float* ws  = (float*)d_ws;

    const int n = in_sizes[0];
    const int L = in_sizes[1];  // 16

    stq_prep<<<1, 64, 0, stream>>>(C, ws, L);

    const int n4 = n / 4;
    const int n_tail = n - n4 * 4;

    int blocks = (n4 + 255) / 256;
    if (blocks > 2048) blocks = 2048;
    if (blocks < 1) blocks = 1;

    stq_main<<<blocks, 256, 0, stream>>>((const vfloat4*)inp, (vfloat4*)out, ws, n4,
                                         inp + n4 * 4, out + n4 * 4, n_tail);
}

// Round 7
// 24.026 us; speedup vs baseline: 1.9133x; 1.9133x over previous
//
#include <hip/hip_runtime.h>
#include <hip/hip_bf16.h>

// SoftToHardQuantize forward == hard quantize (soft path cancels in value).
// Exact np.argmin(|x-C[l]|) semantics via exact thresholds (verified absmax
// 0.0 in R5/R6): per adjacent sorted pair, binary search in ordered-float-bit
// space for the first float where the pairwise argmin predicate (strict <,
// tie -> lower original index) flips.
//
// R6 lesson: 31 "uniform" floats loaded per-thread were NOT scalarized ->
// VGPR spill under 4-deep unroll -> scratch reloads -> 46us.
// R7: ONE fused kernel (no prep launch, no ws round-trip). Per-block preamble
// computes sorted codes + thresholds (parallel rank sort + binsearch, ~1us,
// all blocks resident so paid once in parallel). Codebook forced into SGPRs
// via readfirstlane -> hot loop is 15x(v_cmp+v_cndmask)/elem, zero LDS, low
// VGPR pressure.

#define NCODES 16

typedef float vfloat4 __attribute__((ext_vector_type(4)));

__device__ __forceinline__ unsigned f2o(float f) {
    unsigned u = __float_as_uint(f);
    return (u & 0x80000000u) ? ~u : (u | 0x80000000u);
}
__device__ __forceinline__ float o2f(unsigned o) {
    unsigned u = (o & 0x80000000u) ? (o & 0x7fffffffu) : ~o;
    return __uint_as_float(u);
}
__device__ __forceinline__ float bcast(float v) {  // force SGPR residency
    return __uint_as_float(__builtin_amdgcn_readfirstlane(__float_as_uint(v)));
}

__global__ __launch_bounds__(256) void stq_fused(const vfloat4* __restrict__ in,
                                                 vfloat4* __restrict__ out,
                                                 const float* __restrict__ C,
                                                 int L, int n4,
                                                 const float* __restrict__ in_tail,
                                                 float* __restrict__ out_tail,
                                                 int n_tail) {
    __shared__ float s_sv[NCODES];      // sorted codes
    __shared__ float s_t[NCODES - 1];   // exact thresholds
    __shared__ int   s_ix[NCODES];      // original indices of sorted codes

    const int t = threadIdx.x;

    // ---- per-block preamble: stable rank sort (no register arrays) ----
    if (t < L) {
        float x = C[t];
        int rank = 0;
        for (int j = 0; j < L; ++j) {
            float cj = C[j];
            rank += (cj < x || (cj == x && j < t)) ? 1 : 0;
        }
        s_sv[rank] = x;
        s_ix[rank] = t;
    }
    if (t >= L && t < NCODES) s_sv[t] = 0.0f;  // never selected (T=+inf below)
    __syncthreads();

    if (t < L - 1) {
        float a = s_sv[t], b = s_sv[t + 1];
        int   ia = s_ix[t], ib = s_ix[t + 1];
        float T;
        if (a == b) {
            // duplicate codes: stable sort => ia<ib => lower index always wins.
            // (exact-tie-vs-third-code corner ignored: impossible for random
            // normal codes, and R5/R6 validated absmax 0.0)
            T = __builtin_inff();
        } else {
            // p(x): upper code wins per np.argmin. p(a)=F, p(b)=T, monotone
            // on [a,b] -> binary search in ordered-bit space for first true.
            unsigned lo = f2o(a), hi = f2o(b);
            while (hi - lo > 1u) {
                unsigned mid = lo + (hi - lo) / 2u;
                float x  = o2f(mid);
                float da = fabsf(x - a);
                float db = fabsf(x - b);
                bool p = (db < da) || (db == da && ib < ia);
                if (p) hi = mid; else lo = mid;
            }
            T = o2f(hi);  // smallest float where upper wins: x >= T
        }
        s_t[t] = T;
    }
    if (t >= L - 1 && t < NCODES - 1) s_t[t] = __builtin_inff();
    __syncthreads();

    // ---- broadcast codebook to SGPRs (readfirstlane => wave-uniform) ----
    float SV[NCODES], T[NCODES - 1];
#pragma unroll
    for (int k = 0; k < NCODES; ++k) SV[k] = bcast(s_sv[k]);
#pragma unroll
    for (int k = 0; k < NCODES - 1; ++k) T[k] = bcast(s_t[k]);

    // ---- hot loop: 15x (v_cmp + v_cndmask) per element, all-SGPR operands ----
    const int stride = gridDim.x * blockDim.x;
    int i = blockIdx.x * blockDim.x + t;

#define QUANT1(x) ({ float _q = SV[0]; \
    _Pragma("unroll") \
    for (int _k = 0; _k < NCODES - 1; ++_k) _q = ((x) >= T[_k]) ? SV[_k + 1] : _q; \
    _q; })

    for (; i + 3 * stride < n4; i += 4 * stride) {
        vfloat4 v0 = in[i];
        vfloat4 v1 = in[i + stride];
        vfloat4 v2 = in[i + 2 * stride];
        vfloat4 v3 = in[i + 3 * stride];

        vfloat4 r0, r1, r2, r3;
        r0.x = QUANT1(v0.x); r0.y = QUANT1(v0.y); r0.z = QUANT1(v0.z); r0.w = QUANT1(v0.w);
        r1.x = QUANT1(v1.x); r1.y = QUANT1(v1.y); r1.z = QUANT1(v1.z); r1.w = QUANT1(v1.w);
        r2.x = QUANT1(v2.x); r2.y = QUANT1(v2.y); r2.z = QUANT1(v2.z); r2.w = QUANT1(v2.w);
        r3.x = QUANT1(v3.x); r3.y = QUANT1(v3.y); r3.z = QUANT1(v3.z); r3.w = QUANT1(v3.w);

        __builtin_nontemporal_store(r0, &out[i]);
        __builtin_nontemporal_store(r1, &out[i + stride]);
        __builtin_nontemporal_store(r2, &out[i + 2 * stride]);
        __builtin_nontemporal_store(r3, &out[i + 3 * stride]);
    }
    for (; i < n4; i += stride) {
        vfloat4 v = in[i];
        vfloat4 r;
        r.x = QUANT1(v.x); r.y = QUANT1(v.y); r.z = QUANT1(v.z); r.w = QUANT1(v.w);
        __builtin_nontemporal_store(r, &out[i]);
    }

    int g = blockIdx.x * blockDim.x + t;
    if (g < n_tail) {
        float x = in_tail[g];
        out_tail[g] = QUANT1(x);
    }
#undef QUANT1
}

extern "C" void kernel_launch(void* const* d_in, const int* in_sizes, int n_in,
                              void* d_out, int out_size, void* d_ws, size_t ws_size,
                              hipStream_t stream) {
    const float* inp = (const float*)d_in[0];
    const float* C   = (const float*)d_in[1];
    // d_in[2] = sigma: unused (forward value is exactly the hard quantize)
    float* out = (float*)d_out;

    const int n = in_sizes[0];
    int L = in_sizes[1];
    if (L > NCODES) L = NCODES;

    const int n4 = n / 4;
    const int n_tail = n - n4 * 4;

    int blocks = (n4 + 255) / 256;
    if (blocks > 2048) blocks = 2048;
    if (blocks < 1) blocks = 1;

    stq_fused<<<blocks, 256, 0, stream>>>((const vfloat4*)inp, (vfloat4*)out, C, L, n4,
                                          inp + n4 * 4, out + n4 * 4, n_tail);
}

// Round 8
// 22.744 us; speedup vs baseline: 2.0212x; 1.0564x over previous
//
#include <hip/hip_runtime.h>
#include <hip/hip_bf16.h>

// SoftToHardQuantize forward == hard quantize (soft path cancels in value).
// Exact np.argmin(|x - C[l]|): scan in original order, strict <, fp32.
// (R1 showed surrogate comparisons break at 1-ulp boundaries; scan verified
// absmax 0.0 in R2/R4.)
//
// R8: single-variable A/B vs R4 (18.7us): REGULAR stores instead of
// __builtin_nontemporal_store. Theory: nt bit forces the 32MB output stream
// to HBM every graph replay; without it L2/L3 absorb the write (64MB working
// set << 256MB L3) and the replay runs cache-resident.

#define NCODES 16

typedef float vfloat4 __attribute__((ext_vector_type(4)));

__device__ __forceinline__ vfloat4 quant4(vfloat4 v, const float* c) {
    float x0 = v.x, x1 = v.y, x2 = v.z, x3 = v.w;
    float b0 = fabsf(x0 - c[0]), b1 = fabsf(x1 - c[0]);
    float b2 = fabsf(x2 - c[0]), b3 = fabsf(x3 - c[0]);
    float q0 = c[0], q1 = c[0], q2 = c[0], q3 = c[0];
#pragma unroll
    for (int l = 1; l < NCODES; ++l) {
        float cl = c[l];
        float d0 = fabsf(x0 - cl);
        float d1 = fabsf(x1 - cl);
        float d2 = fabsf(x2 - cl);
        float d3 = fabsf(x3 - cl);
        if (d0 < b0) { b0 = d0; q0 = cl; }  // strict <: first min wins (np.argmin)
        if (d1 < b1) { b1 = d1; q1 = cl; }
        if (d2 < b2) { b2 = d2; q2 = cl; }
        if (d3 < b3) { b3 = d3; q3 = cl; }
    }
    vfloat4 r;
    r.x = q0; r.y = q1; r.z = q2; r.w = q3;
    return r;
}

__global__ __launch_bounds__(256) void stq_main(const vfloat4* __restrict__ in,
                                                vfloat4* __restrict__ out,
                                                const float* __restrict__ C,
                                                int n4,
                                                const float* __restrict__ in_tail,
                                                float* __restrict__ out_tail,
                                                int n_tail) {
    // Uniform codebook -> SGPRs
    float c[NCODES];
#pragma unroll
    for (int l = 0; l < NCODES; ++l) c[l] = C[l];

    const int stride = gridDim.x * blockDim.x;
    int i = blockIdx.x * blockDim.x + threadIdx.x;

    // 4-deep: issue all 4 loads before any compute (64B/thread in flight)
    for (; i + 3 * stride < n4; i += 4 * stride) {
        vfloat4 v0 = in[i];
        vfloat4 v1 = in[i + stride];
        vfloat4 v2 = in[i + 2 * stride];
        vfloat4 v3 = in[i + 3 * stride];
        vfloat4 r0 = quant4(v0, c);
        vfloat4 r1 = quant4(v1, c);
        vfloat4 r2 = quant4(v2, c);
        vfloat4 r3 = quant4(v3, c);
        out[i]              = r0;
        out[i + stride]     = r1;
        out[i + 2 * stride] = r2;
        out[i + 3 * stride] = r3;
    }
    // remainder float4s
    for (; i < n4; i += stride) {
        out[i] = quant4(in[i], c);
    }

    // scalar tail (n not divisible by 4)
    int t = blockIdx.x * blockDim.x + threadIdx.x;
    if (t < n_tail) {
        float x = in_tail[t];
        float b = fabsf(x - c[0]);
        float q = c[0];
#pragma unroll
        for (int l = 1; l < NCODES; ++l) {
            float d = fabsf(x - c[l]);
            if (d < b) { b = d; q = c[l]; }
        }
        out_tail[t] = q;
    }
}

extern "C" void kernel_launch(void* const* d_in, const int* in_sizes, int n_in,
                              void* d_out, int out_size, void* d_ws, size_t ws_size,
                              hipStream_t stream) {
    const float* inp = (const float*)d_in[0];
    const float* C   = (const float*)d_in[1];
    // d_in[2] = sigma: unused (forward value is exactly the hard quantize)
    float* out = (float*)d_out;

    const int n = in_sizes[0];
    const int n4 = n / 4;
    const int n_tail = n - n4 * 4;

    int blocks = (n4 + 255) / 256;
    if (blocks > 2048) blocks = 2048;
    if (blocks < 1) blocks = 1;

    stq_main<<<blocks, 256, 0, stream>>>((const vfloat4*)inp, (vfloat4*)out, C, n4,
                                         inp + n4 * 4, out + n4 * 4, n_tail);
}

// Round 9
// 19.726 us; speedup vs baseline: 2.3304x; 1.1530x over previous
//
#include <hip/hip_runtime.h>
#include <hip/hip_bf16.h>

// SoftToHardQuantize forward == hard quantize (soft path cancels in value).
// Exact np.argmin(|x - C[l]|): scan in original order, strict <, fp32
// (verified absmax 0.0 in R2/R4/R8).
//
// Evidence so far: NT stores -4us (R8 vs R4: L2 write-allocate thrash);
// 4-deep strided unroll +2us (R2 vs R8: 4 streams 8MB apart, worse DRAM
// locality). Not VALU-bound (R7 threshold chain, half the ops, no win).
// R9: simplest memory shape -- one float4/thread, exact grid, no loop,
// contiguous sweep, NT stores. TLP (32 waves/CU) hides load latency.

#define NCODES 16

typedef float vfloat4 __attribute__((ext_vector_type(4)));

__device__ __forceinline__ vfloat4 quant4(vfloat4 v, const float* c) {
    float x0 = v.x, x1 = v.y, x2 = v.z, x3 = v.w;
    float b0 = fabsf(x0 - c[0]), b1 = fabsf(x1 - c[0]);
    float b2 = fabsf(x2 - c[0]), b3 = fabsf(x3 - c[0]);
    float q0 = c[0], q1 = c[0], q2 = c[0], q3 = c[0];
#pragma unroll
    for (int l = 1; l < NCODES; ++l) {
        float cl = c[l];
        float d0 = fabsf(x0 - cl);
        float d1 = fabsf(x1 - cl);
        float d2 = fabsf(x2 - cl);
        float d3 = fabsf(x3 - cl);
        if (d0 < b0) { b0 = d0; q0 = cl; }  // strict <: first min wins (np.argmin)
        if (d1 < b1) { b1 = d1; q1 = cl; }
        if (d2 < b2) { b2 = d2; q2 = cl; }
        if (d3 < b3) { b3 = d3; q3 = cl; }
    }
    vfloat4 r;
    r.x = q0; r.y = q1; r.z = q2; r.w = q3;
    return r;
}

__global__ __launch_bounds__(256) void stq_main(const vfloat4* __restrict__ in,
                                                vfloat4* __restrict__ out,
                                                const float* __restrict__ C,
                                                int n4,
                                                const float* __restrict__ in_tail,
                                                float* __restrict__ out_tail,
                                                int n_tail) {
    // Uniform codebook -> SGPRs (s_load)
    float c[NCODES];
#pragma unroll
    for (int l = 0; l < NCODES; ++l) c[l] = C[l];

    const int i = blockIdx.x * blockDim.x + threadIdx.x;
    if (i < n4) {
        vfloat4 r = quant4(in[i], c);
        __builtin_nontemporal_store(r, &out[i]);
    }

    // scalar tail (n not divisible by 4) — only first block's threads
    if (blockIdx.x == 0 && threadIdx.x < n_tail) {
        float x = in_tail[threadIdx.x];
        float b = fabsf(x - c[0]);
        float q = c[0];
#pragma unroll
        for (int l = 1; l < NCODES; ++l) {
            float d = fabsf(x - c[l]);
            if (d < b) { b = d; q = c[l]; }
        }
        out_tail[threadIdx.x] = q;
    }
}

extern "C" void kernel_launch(void* const* d_in, const int* in_sizes, int n_in,
                              void* d_out, int out_size, void* d_ws, size_t ws_size,
                              hipStream_t stream) {
    const float* inp = (const float*)d_in[0];
    const float* C   = (const float*)d_in[1];
    // d_in[2] = sigma: unused (forward value is exactly the hard quantize)
    float* out = (float*)d_out;

    const int n = in_sizes[0];
    const int n4 = n / 4;
    const int n_tail = n - n4 * 4;

    int blocks = (n4 + 255) / 256;   // exact grid: one float4 per thread
    if (blocks < 1) blocks = 1;

    stq_main<<<blocks, 256, 0, stream>>>((const vfloat4*)inp, (vfloat4*)out, C, n4,
                                         inp + n4 * 4, out + n4 * 4, n_tail);
}

// Round 10
// 18.558 us; speedup vs baseline: 2.4771x; 1.0629x over previous
//
#include <hip/hip_runtime.h>
#include <hip/hip_bf16.h>

// SoftToHardQuantize forward == hard quantize (soft path cancels in value).
// Exact np.argmin(|x - C[l]|): scan in original order, strict <, fp32
// (verified absmax 0.0 in R2/R4/R8/R9).
//
// Ledger: NT stores -4us (R8->R4); 4-deep ILP +1us under NT (R9->R4);
// compute-op count irrelevant (R7). Best = R4 18.7us vs 10.6us copy roofline.
// R10: disambiguate fixed-overhead vs access-pattern. Block-contiguous
// layout: each block owns 16KB (256 thr x 4 float4 at +0/+256/+512/+768),
// exact grid, no loop. If dur unchanged -> overhead floor -> roofline.

#define NCODES 16
#define PER_BLOCK 1024  // float4s per block = 256 threads * 4

typedef float vfloat4 __attribute__((ext_vector_type(4)));

__device__ __forceinline__ vfloat4 quant4(vfloat4 v, const float* c) {
    float x0 = v.x, x1 = v.y, x2 = v.z, x3 = v.w;
    float b0 = fabsf(x0 - c[0]), b1 = fabsf(x1 - c[0]);
    float b2 = fabsf(x2 - c[0]), b3 = fabsf(x3 - c[0]);
    float q0 = c[0], q1 = c[0], q2 = c[0], q3 = c[0];
#pragma unroll
    for (int l = 1; l < NCODES; ++l) {
        float cl = c[l];
        float d0 = fabsf(x0 - cl);
        float d1 = fabsf(x1 - cl);
        float d2 = fabsf(x2 - cl);
        float d3 = fabsf(x3 - cl);
        if (d0 < b0) { b0 = d0; q0 = cl; }  // strict <: first min wins (np.argmin)
        if (d1 < b1) { b1 = d1; q1 = cl; }
        if (d2 < b2) { b2 = d2; q2 = cl; }
        if (d3 < b3) { b3 = d3; q3 = cl; }
    }
    vfloat4 r;
    r.x = q0; r.y = q1; r.z = q2; r.w = q3;
    return r;
}

__global__ __launch_bounds__(256) void stq_main(const vfloat4* __restrict__ in,
                                                vfloat4* __restrict__ out,
                                                const float* __restrict__ C,
                                                int n4,
                                                const float* __restrict__ in_tail,
                                                float* __restrict__ out_tail,
                                                int n_tail) {
    // Uniform codebook -> SGPRs
    float c[NCODES];
#pragma unroll
    for (int l = 0; l < NCODES; ++l) c[l] = C[l];

    const int base = blockIdx.x * PER_BLOCK + threadIdx.x;

    if (base + 768 < n4) {
        // fast path: all 4 loads issued back-to-back, contiguous 16KB block
        vfloat4 v0 = in[base];
        vfloat4 v1 = in[base + 256];
        vfloat4 v2 = in[base + 512];
        vfloat4 v3 = in[base + 768];
        vfloat4 r0 = quant4(v0, c);
        vfloat4 r1 = quant4(v1, c);
        vfloat4 r2 = quant4(v2, c);
        vfloat4 r3 = quant4(v3, c);
        __builtin_nontemporal_store(r0, &out[base]);
        __builtin_nontemporal_store(r1, &out[base + 256]);
        __builtin_nontemporal_store(r2, &out[base + 512]);
        __builtin_nontemporal_store(r3, &out[base + 768]);
    } else {
#pragma unroll
        for (int k = 0; k < 4; ++k) {
            int i = base + k * 256;
            if (i < n4) {
                vfloat4 r = quant4(in[i], c);
                __builtin_nontemporal_store(r, &out[i]);
            }
        }
    }

    // scalar tail (n not divisible by 4) — first block only
    if (blockIdx.x == 0 && threadIdx.x < n_tail) {
        float x = in_tail[threadIdx.x];
        float b = fabsf(x - c[0]);
        float q = c[0];
#pragma unroll
        for (int l = 1; l < NCODES; ++l) {
            float d = fabsf(x - c[l]);
            if (d < b) { b = d; q = c[l]; }
        }
        out_tail[threadIdx.x] = q;
    }
}

extern "C" void kernel_launch(void* const* d_in, const int* in_sizes, int n_in,
                              void* d_out, int out_size, void* d_ws, size_t ws_size,
                              hipStream_t stream) {
    const float* inp = (const float*)d_in[0];
    const float* C   = (const float*)d_in[1];
    // d_in[2] = sigma: unused (forward value is exactly the hard quantize)
    float* out = (float*)d_out;

    const int n = in_sizes[0];
    const int n4 = n / 4;
    const int n_tail = n - n4 * 4;

    int blocks = (n4 + PER_BLOCK - 1) / PER_BLOCK;
    if (blocks < 1) blocks = 1;

    stq_main<<<blocks, 256, 0, stream>>>((const vfloat4*)inp, (vfloat4*)out, C, n4,
                                         inp + n4 * 4, out + n4 * 4, n_tail);
}